// Round 5
// baseline (8281.523 us; speedup 1.0000x reference)
//
#include <hip/hip_runtime.h>
#include <math.h>

// MACE layer, f32. Round 5: de-spill k_edge. R4 post-mortem: 9.3GB WRITE with
// only 64MB logical writes = scratch spill traffic (demand ~160 regs vs 128 cap).
// Fix: path-grouped phase B — es-group {p0,p2} then ev-group {p1,p3,p4}; apply
// TP per path and flush directly into LDS tile atomics (bank-rotated). No
// per-edge m accumulators, no run-merge => peak ~105 VGPRs, no spills.
// K1: node pre   Ksort: hist/scan/permute   K2: node-owned fused edge kernel
// K3: epilogue

#define N_NODES 32768
#define N_EDGES 524288
#define FCH 128
#define NBASIS 8
#define HDIM 64
#define CE 64      // edge chunk per block in K2
#define NB 4       // receiver nodes owned per block in K2
#define NT1 8      // nodes per block in K1/K3

__device__ __forceinline__ float silu(float x) { return x / (1.0f + __expf(-x)); }

constexpr float INV_SQRT128  = 0.08838834764831845f;
constexpr float INV_SQRT8    = 0.35355339059327373f;
constexpr float INV_64       = 0.125f;                 // 1/sqrt(64)
constexpr float INV_SQRT3    = 0.5773502691896258f;
constexpr float INV_SQRT2    = 0.7071067811865476f;
constexpr float INV_SQRT10   = 0.31622776601683794f;
constexpr float INV_SQRT1280 = 0.027950849718747374f;  // 1/sqrt(F*Z)
constexpr float INV_SQRT16   = 0.25f;
constexpr float EPSN         = 0.125f;

// ---------------------------------------------------------------- K1: node pre
__global__ __launch_bounds__(128) void k_node_pre(
    const float* __restrict__ ns, const float* __restrict__ nv,
    const float* __restrict__ w_skip, const float* __restrict__ w_up0,
    const float* __restrict__ w_up1, const int* __restrict__ species,
    float* __restrict__ hs, float* __restrict__ hv0, float* __restrict__ hv1,
    float* __restrict__ hv2, float* __restrict__ self_conn)
{
    __shared__ float ls[NT1][FCH];
    __shared__ float lv[3][NT1][FCH];
    __shared__ int lsp[NT1];
    const int g  = threadIdx.x;
    const int n0 = blockIdx.x * NT1;

    #pragma unroll
    for (int n = 0; n < NT1; ++n)
        ls[n][g] = ns[(size_t)(n0 + n) * FCH + g];
    // float3-contiguous read, plane-separated LDS write (conflict-free)
    for (int idx = g; idx < NT1 * FCH; idx += 128) {
        int n = idx >> 7, f = idx & 127;
        const float* src = nv + ((size_t)(n0 + n) * FCH + f) * 3;
        lv[0][n][f] = src[0];
        lv[1][n][f] = src[1];
        lv[2][n][f] = src[2];
    }
    if (g < NT1) lsp[g] = species[n0 + g];
    __syncthreads();

    const float* wk[NT1];
    #pragma unroll
    for (int n = 0; n < NT1; ++n)
        wk[n] = w_skip + (size_t)lsp[n] * FCH * FCH + g;

    float a_s[NT1], a0[NT1], a1[NT1], a2[NT1], a_k[NT1];
    #pragma unroll
    for (int n = 0; n < NT1; ++n) { a_s[n]=0; a0[n]=0; a1[n]=0; a2[n]=0; a_k[n]=0; }

    #pragma unroll 2
    for (int f = 0; f < FCH; ++f) {
        float u0 = w_up0[f * FCH + g];
        float u1 = w_up1[f * FCH + g];
        #pragma unroll
        for (int n = 0; n < NT1; ++n) {
            float s = ls[n][f];
            a_s[n] += s * u0;
            a0[n]  += lv[0][n][f] * u1;
            a1[n]  += lv[1][n][f] * u1;
            a2[n]  += lv[2][n][f] * u1;
            a_k[n] += s * wk[n][(size_t)f * FCH];
        }
    }
    #pragma unroll
    for (int n = 0; n < NT1; ++n) {
        size_t o = (size_t)(n0 + n) * FCH + g;
        hs[o]  = a_s[n] * INV_SQRT128;
        hv0[o] = a0[n]  * INV_SQRT128;
        hv1[o] = a1[n]  * INV_SQRT128;
        hv2[o] = a2[n]  * INV_SQRT128;
        self_conn[o] = a_k[n] * INV_SQRT1280;
    }
}

// ---------------------------------------------------------------- sort kernels
__global__ __launch_bounds__(256) void k_hist(
    const int* __restrict__ recv, int* __restrict__ counts)
{
    int e = blockIdx.x * 256 + threadIdx.x;
    atomicAdd(&counts[recv[e]], 1);
}

__global__ __launch_bounds__(1024) void k_scan(
    const int* __restrict__ counts, int* __restrict__ cursor)
{
    __shared__ int part[1024];
    const int t  = threadIdx.x;
    const int b0 = t * 32;
    int local[32];
    int s = 0;
    #pragma unroll
    for (int i = 0; i < 32; ++i) { local[i] = s; s += counts[b0 + i]; }
    part[t] = s;
    __syncthreads();
    for (int off = 1; off < 1024; off <<= 1) {
        int v   = part[t];
        int add = (t >= off) ? part[t - off] : 0;
        __syncthreads();
        part[t] = v + add;
        __syncthreads();
    }
    int base = (t == 0) ? 0 : part[t - 1];
    #pragma unroll
    for (int i = 0; i < 32; ++i) cursor[b0 + i] = base + local[i];
}

__global__ __launch_bounds__(256) void k_permute(
    const int* __restrict__ recv, int* __restrict__ cursor,
    int* __restrict__ perm)
{
    int e = blockIdx.x * 256 + threadIdx.x;
    int pos = atomicAdd(&cursor[recv[e]], 1);
    perm[pos] = e;
}

// ---------------------------------------------------------------- K2: edges
// Block owns nodes [blockIdx.x*NB, +NB); their in-edges are contiguous in perm.
// LDS-tile accumulation, plain final stores. No global atomics, no spills.
__global__ __launch_bounds__(256, 2) void k_edge(
    const float* __restrict__ vectors, const float* __restrict__ radial,
    const float* __restrict__ w1, const float* __restrict__ w2,
    const float* __restrict__ w3, const float* __restrict__ w4,
    const float* __restrict__ hs, const float* __restrict__ hv0,
    const float* __restrict__ hv1, const float* __restrict__ hv2,
    const int* __restrict__ senders, const int* __restrict__ receivers,
    const int* __restrict__ row_end, const int* __restrict__ perm,
    float* __restrict__ agg_s, float* __restrict__ agg_v0,
    float* __restrict__ agg_v1, float* __restrict__ agg_v2)
{
    __shared__ __align__(16) float lrad[CE * NBASIS];   // 2KB
    __shared__ __align__(16) float hA[CE * HDIM];       // 16KB
    __shared__ __align__(16) float hB[CE * HDIM];       // 16KB
    __shared__ __align__(16) float w4lds[HDIM * FCH];   // 32KB (one path slice)
    __shared__ float lY[CE][3];
    __shared__ int leid[CE], lsend[CE], lnl[CE];
    __shared__ __align__(16) float laccS[NB * FCH];     // 2KB each
    __shared__ __align__(16) float laccV0[NB * FCH];
    __shared__ __align__(16) float laccV1[NB * FCH];
    __shared__ __align__(16) float laccV2[NB * FCH];
    __shared__ int sse[2];

    const int tid   = threadIdx.x;
    const int nbase = blockIdx.x * NB;

    if (tid == 0) {
        sse[0] = (nbase == 0) ? 0 : row_end[nbase - 1];
        sse[1] = row_end[nbase + NB - 1];
    }
    for (int i = tid; i < NB * FCH; i += 256) {
        laccS[i] = 0.f; laccV0[i] = 0.f; laccV1[i] = 0.f; laccV2[i] = 0.f;
    }
    __syncthreads();
    const int start = sse[0], end = sse[1];

    const int k   = tid & 63;
    const int grp = tid >> 6;       // wave id, 16 edge slots each (phase A)
    const int fq  = (tid & 31) * 4; // channel quad base
    const int eg  = tid >> 5;       // 0..7, 8 edge slots each (phase B)
    const int rot = (tid >> 3) & 3; // bank rotation for LDS-tile atomics

    for (int c0 = start; c0 < end; c0 += CE) {
        const int nc = min(CE, end - c0);

        __syncthreads();
        if (tid < CE) leid[tid] = (tid < nc) ? perm[c0 + tid] : -1;
        __syncthreads();
        if (tid < CE) {
            int eid = leid[tid];
            if (eid >= 0) {
                float vx = vectors[(size_t)eid * 3 + 0];
                float vy = vectors[(size_t)eid * 3 + 1];
                float vz = vectors[(size_t)eid * 3 + 2];
                float rn = 1.0f / (sqrtf(vx * vx + vy * vy + vz * vz) + 1e-9f);
                lY[tid][0] = vx * rn; lY[tid][1] = vy * rn; lY[tid][2] = vz * rn;
                lsend[tid] = senders[eid];
                lnl[tid]   = receivers[eid] - nbase;   // 0..NB-1
            } else {
                lY[tid][0] = 0.f; lY[tid][1] = 0.f; lY[tid][2] = 0.f;
                lsend[tid] = 0;
                lnl[tid]   = -1;
            }
        }
        for (int idx = tid; idx < CE * NBASIS; idx += 256) {
            int slot = idx >> 3;
            int eid  = leid[slot];
            lrad[idx] = (eid >= 0) ? radial[(size_t)eid * NBASIS + (idx & 7)] : 0.f;
        }
        __syncthreads();

        const int e_lo = grp * 16;
        const int e_hi = min(e_lo + 16, nc);

        // radial MLP: layer 1 (8->64)
        if (e_lo < nc) {
            float w1c[NBASIS];
            #pragma unroll
            for (int j = 0; j < NBASIS; ++j) w1c[j] = w1[j * HDIM + k];
            for (int e = e_lo; e < e_hi; ++e) {
                float acc = 0.f;
                #pragma unroll
                for (int j = 0; j < NBASIS; ++j) acc += lrad[e * NBASIS + j] * w1c[j];
                hA[e * HDIM + k] = silu(acc * INV_SQRT8);
            }
        }
        __syncthreads();
        // layer 2 (64->64)
        if (e_lo < nc) {
            float wc[HDIM];
            #pragma unroll
            for (int j = 0; j < HDIM; ++j) wc[j] = w2[j * HDIM + k];
            for (int e = e_lo; e < e_hi; ++e) {
                float acc = 0.f;
                #pragma unroll
                for (int j = 0; j < HDIM; ++j) acc += hA[e * HDIM + j] * wc[j];
                hB[e * HDIM + k] = silu(acc * INV_64);
            }
        }
        __syncthreads();
        // layer 3 (64->64)
        if (e_lo < nc) {
            float wc[HDIM];
            #pragma unroll
            for (int j = 0; j < HDIM; ++j) wc[j] = w3[j * HDIM + k];
            for (int e = e_lo; e < e_hi; ++e) {
                float acc = 0.f;
                #pragma unroll
                for (int j = 0; j < HDIM; ++j) acc += hB[e * HDIM + j] * wc[j];
                hA[e * HDIM + k] = silu(acc * INV_64);
            }
        }
        __syncthreads();

        // Phase B: per 4-edge tile, path-grouped; flush straight into LDS tile.
        for (int half = 0; half < 2; ++half) {
            const int e_base = eg * 8 + half * 4;
            const bool act = e_base < nc;
            int eL[4];
            #pragma unroll
            for (int q = 0; q < 4; ++q) eL[q] = e_base + q;

            // ---------- es group: paths 0 (->S) and 2 (->V) ----------
            {
                float es[4][4];
                if (act) {
                    #pragma unroll
                    for (int q = 0; q < 4; ++q) {
                        float4 t = *(const float4*)(hs + (size_t)lsend[eL[q]] * FCH + fq);
                        es[q][0]=t.x; es[q][1]=t.y; es[q][2]=t.z; es[q][3]=t.w;
                    }
                }
                #pragma unroll
                for (int pi = 0; pi < 2; ++pi) {
                    const int p = (pi == 0) ? 0 : 2;
                    __syncthreads();
                    for (int idx = tid; idx < HDIM * 32; idx += 256) {
                        int j = idx >> 5;
                        int f = (idx & 31) * 4;
                        *(float4*)&w4lds[j * FCH + f] =
                            *(const float4*)(w4 + (size_t)j * 640 + p * FCH + f);
                    }
                    __syncthreads();
                    if (!act) continue;

                    float mx[4][4];
                    #pragma unroll
                    for (int q = 0; q < 4; ++q)
                        #pragma unroll
                        for (int c = 0; c < 4; ++c) mx[q][c] = 0;
                    for (int j4 = 0; j4 < 16; ++j4) {
                        float4 wj0 = *(float4*)&w4lds[(j4 * 4 + 0) * FCH + fq];
                        float4 wj1 = *(float4*)&w4lds[(j4 * 4 + 1) * FCH + fq];
                        float4 wj2 = *(float4*)&w4lds[(j4 * 4 + 2) * FCH + fq];
                        float4 wj3 = *(float4*)&w4lds[(j4 * 4 + 3) * FCH + fq];
                        #pragma unroll
                        for (int q = 0; q < 4; ++q) {
                            float4 h4 = *(float4*)&hA[eL[q] * HDIM + j4 * 4];
                            mx[q][0] += h4.x*wj0.x + h4.y*wj1.x + h4.z*wj2.x + h4.w*wj3.x;
                            mx[q][1] += h4.x*wj0.y + h4.y*wj1.y + h4.z*wj2.y + h4.w*wj3.y;
                            mx[q][2] += h4.x*wj0.z + h4.y*wj1.z + h4.z*wj2.z + h4.w*wj3.z;
                            mx[q][3] += h4.x*wj0.w + h4.y*wj1.w + h4.z*wj2.w + h4.w*wj3.w;
                        }
                    }
                    #pragma unroll
                    for (int q = 0; q < 4; ++q) {
                        int nl = lnl[eL[q]];
                        if (nl < 0) continue;
                        int b = nl * FCH + fq;
                        if (p == 0) {
                            #pragma unroll
                            for (int c = 0; c < 4; ++c) {
                                int cc = (c + rot) & 3;
                                atomicAdd(&laccS[b + cc], mx[q][cc] * es[q][cc]);
                            }
                        } else {
                            float Yx = lY[eL[q]][0], Yy = lY[eL[q]][1], Yz = lY[eL[q]][2];
                            #pragma unroll
                            for (int c = 0; c < 4; ++c) {
                                int cc = (c + rot) & 3;
                                float t = mx[q][cc] * es[q][cc];
                                atomicAdd(&laccV0[b + cc], t * Yx);
                                atomicAdd(&laccV1[b + cc], t * Yy);
                                atomicAdd(&laccV2[b + cc], t * Yz);
                            }
                        }
                    }
                }
            }

            // ---------- ev group: paths 1 (->S), 3, 4 (->V) ----------
            {
                float ev0[4][4], ev1[4][4], ev2[4][4];
                if (act) {
                    #pragma unroll
                    for (int q = 0; q < 4; ++q) {
                        size_t o = (size_t)lsend[eL[q]] * FCH + fq;
                        float4 t;
                        t = *(const float4*)(hv0 + o);
                        ev0[q][0]=t.x; ev0[q][1]=t.y; ev0[q][2]=t.z; ev0[q][3]=t.w;
                        t = *(const float4*)(hv1 + o);
                        ev1[q][0]=t.x; ev1[q][1]=t.y; ev1[q][2]=t.z; ev1[q][3]=t.w;
                        t = *(const float4*)(hv2 + o);
                        ev2[q][0]=t.x; ev2[q][1]=t.y; ev2[q][2]=t.z; ev2[q][3]=t.w;
                    }
                }
                #pragma unroll
                for (int pi = 0; pi < 3; ++pi) {
                    const int p = (pi == 0) ? 1 : (pi == 1) ? 3 : 4;
                    __syncthreads();
                    for (int idx = tid; idx < HDIM * 32; idx += 256) {
                        int j = idx >> 5;
                        int f = (idx & 31) * 4;
                        *(float4*)&w4lds[j * FCH + f] =
                            *(const float4*)(w4 + (size_t)j * 640 + p * FCH + f);
                    }
                    __syncthreads();
                    if (!act) continue;

                    float mx[4][4];
                    #pragma unroll
                    for (int q = 0; q < 4; ++q)
                        #pragma unroll
                        for (int c = 0; c < 4; ++c) mx[q][c] = 0;
                    for (int j4 = 0; j4 < 16; ++j4) {
                        float4 wj0 = *(float4*)&w4lds[(j4 * 4 + 0) * FCH + fq];
                        float4 wj1 = *(float4*)&w4lds[(j4 * 4 + 1) * FCH + fq];
                        float4 wj2 = *(float4*)&w4lds[(j4 * 4 + 2) * FCH + fq];
                        float4 wj3 = *(float4*)&w4lds[(j4 * 4 + 3) * FCH + fq];
                        #pragma unroll
                        for (int q = 0; q < 4; ++q) {
                            float4 h4 = *(float4*)&hA[eL[q] * HDIM + j4 * 4];
                            mx[q][0] += h4.x*wj0.x + h4.y*wj1.x + h4.z*wj2.x + h4.w*wj3.x;
                            mx[q][1] += h4.x*wj0.y + h4.y*wj1.y + h4.z*wj2.y + h4.w*wj3.y;
                            mx[q][2] += h4.x*wj0.z + h4.y*wj1.z + h4.z*wj2.z + h4.w*wj3.z;
                            mx[q][3] += h4.x*wj0.w + h4.y*wj1.w + h4.z*wj2.w + h4.w*wj3.w;
                        }
                    }
                    #pragma unroll
                    for (int q = 0; q < 4; ++q) {
                        int nl = lnl[eL[q]];
                        if (nl < 0) continue;
                        int b = nl * FCH + fq;
                        float Yx = lY[eL[q]][0], Yy = lY[eL[q]][1], Yz = lY[eL[q]][2];
                        if (p == 1) {
                            #pragma unroll
                            for (int c = 0; c < 4; ++c) {
                                int cc = (c + rot) & 3;
                                float d = ev0[q][cc]*Yx + ev1[q][cc]*Yy + ev2[q][cc]*Yz;
                                atomicAdd(&laccS[b + cc], mx[q][cc] * d * INV_SQRT3);
                            }
                        } else if (p == 3) {
                            #pragma unroll
                            for (int c = 0; c < 4; ++c) {
                                int cc = (c + rot) & 3;
                                float m = mx[q][cc];
                                atomicAdd(&laccV0[b + cc], m * ev0[q][cc]);
                                atomicAdd(&laccV1[b + cc], m * ev1[q][cc]);
                                atomicAdd(&laccV2[b + cc], m * ev2[q][cc]);
                            }
                        } else {
                            #pragma unroll
                            for (int c = 0; c < 4; ++c) {
                                int cc = (c + rot) & 3;
                                float m = mx[q][cc] * INV_SQRT2;
                                float cx = ev1[q][cc]*Yz - ev2[q][cc]*Yy;
                                float cy = ev2[q][cc]*Yx - ev0[q][cc]*Yz;
                                float cz = ev0[q][cc]*Yy - ev1[q][cc]*Yx;
                                atomicAdd(&laccV0[b + cc], m * cx);
                                atomicAdd(&laccV1[b + cc], m * cy);
                                atomicAdd(&laccV2[b + cc], m * cz);
                            }
                        }
                    }
                }
            }
        } // half
    } // chunk

    __syncthreads();
    for (int i = tid; i < NB * FCH; i += 256) {
        int nl = i >> 7;
        int ch = i & 127;
        size_t o = (size_t)(nbase + nl) * FCH + ch;
        agg_s[o]  = laccS[i]  * INV_64;
        agg_v0[o] = laccV0[i] * INV_64;
        agg_v1[o] = laccV1[i] * INV_64;
        agg_v2[o] = laccV2[i] * INV_64;
    }
}

// ---------------------------------------------------------------- K3: epilogue
__global__ __launch_bounds__(128) void k_epilogue(
    const float* __restrict__ agg_s, const float* __restrict__ agg_v0,
    const float* __restrict__ agg_v1, const float* __restrict__ agg_v2,
    const float* __restrict__ self_conn, const int* __restrict__ species,
    const float* __restrict__ w_down0, const float* __restrict__ w_down1,
    const float* __restrict__ w_sc, const float* __restrict__ w_post,
    const float* __restrict__ w_read1, const float* __restrict__ w_read2,
    float* __restrict__ out0, float* __restrict__ feats_out)
{
    __shared__ float lS[NT1][FCH];
    __shared__ float lV[3][NT1][FCH];
    __shared__ float fA[NT1][FCH];
    __shared__ float fB[NT1][FCH];
    __shared__ int lsp[NT1];
    const int g  = threadIdx.x;
    const int n0 = blockIdx.x * NT1;

    #pragma unroll
    for (int n = 0; n < NT1; ++n) {
        size_t o = (size_t)(n0 + n) * FCH + g;
        lS[n][g]    = agg_s[o]  * EPSN;
        lV[0][n][g] = agg_v0[o] * EPSN;
        lV[1][n][g] = agg_v1[o] * EPSN;
        lV[2][n][g] = agg_v2[o] * EPSN;
    }
    if (g < NT1) lsp[g] = species[n0 + g];
    __syncthreads();

    float xs[NT1], xv0[NT1], xv1[NT1], xv2[NT1];
    #pragma unroll
    for (int n = 0; n < NT1; ++n) { xs[n]=0; xv0[n]=0; xv1[n]=0; xv2[n]=0; }
    #pragma unroll 2
    for (int f = 0; f < FCH; ++f) {
        float d0 = w_down0[f * FCH + g];
        float d1 = w_down1[f * FCH + g];
        #pragma unroll
        for (int n = 0; n < NT1; ++n) {
            xs[n]  += lS[n][f] * d0;
            xv0[n] += lV[0][n][f] * d1;
            xv1[n] += lV[1][n][f] * d1;
            xv2[n] += lV[2][n][f] * d1;
        }
    }
    #pragma unroll
    for (int n = 0; n < NT1; ++n) {
        float s  = xs[n]  * INV_SQRT128;
        float v0 = xv0[n] * INV_SQRT128;
        float v1 = xv1[n] * INV_SQRT128;
        float v2 = xv2[n] * INV_SQRT128;
        int z = lsp[n];
        float wz0 = w_sc[((size_t)z * 3 + 0) * FCH + g] * INV_SQRT10;
        float wz1 = w_sc[((size_t)z * 3 + 1) * FCH + g] * INV_SQRT10;
        float wz2 = w_sc[((size_t)z * 3 + 2) * FCH + g] * INV_SQRT10;
        fA[n][g] = wz0 * s + wz1 * s * s + wz2 * (v0*v0 + v1*v1 + v2*v2);
    }
    __syncthreads();

    float fc[NT1];
    #pragma unroll
    for (int n = 0; n < NT1; ++n) fc[n] = 0;
    #pragma unroll 2
    for (int f = 0; f < FCH; ++f) {
        float wp = w_post[f * FCH + g];
        #pragma unroll
        for (int n = 0; n < NT1; ++n) fc[n] += fA[n][f] * wp;
    }
    #pragma unroll
    for (int n = 0; n < NT1; ++n) {
        size_t o = (size_t)(n0 + n) * FCH + g;
        float v = fc[n] * INV_SQRT128 + self_conn[o];
        fB[n][g] = v;
        feats_out[o] = v;
    }
    __syncthreads();

    const int n2 = g >> 4, r = g & 15;
    float acc = 0.f;
    for (int f = 0; f < FCH; ++f) acc += fB[n2][f] * w_read1[f * 16 + r];
    float t = silu(acc * INV_SQRT128);
    float val = t * w_read2[r];
    val += __shfl_down(val, 8, 16);
    val += __shfl_down(val, 4, 16);
    val += __shfl_down(val, 2, 16);
    val += __shfl_down(val, 1, 16);
    if (r == 0) out0[n0 + n2] = val * INV_SQRT16;
}

// ---------------------------------------------------------------- launch
extern "C" void kernel_launch(void* const* d_in, const int* in_sizes, int n_in,
                              void* d_out, int out_size, void* d_ws, size_t ws_size,
                              hipStream_t stream) {
    (void)in_sizes; (void)n_in; (void)out_size; (void)ws_size;
    const float* vectors      = (const float*)d_in[0];
    const float* node_scalars = (const float*)d_in[1];
    const float* node_vectors = (const float*)d_in[2];
    const float* radial       = (const float*)d_in[3];
    const float* w_skip       = (const float*)d_in[4];
    const float* w_up0        = (const float*)d_in[5];
    const float* w_up1        = (const float*)d_in[6];
    const float* mlp_w1       = (const float*)d_in[7];
    const float* mlp_w2       = (const float*)d_in[8];
    const float* mlp_w3       = (const float*)d_in[9];
    const float* mlp_w4       = (const float*)d_in[10];
    const float* w_down0      = (const float*)d_in[11];
    const float* w_down1      = (const float*)d_in[12];
    const float* w_sc         = (const float*)d_in[13];
    const float* w_post       = (const float*)d_in[14];
    const float* w_read1      = (const float*)d_in[15];
    const float* w_read2      = (const float*)d_in[16];
    const int*   senders      = (const int*)d_in[17];
    const int*   receivers    = (const int*)d_in[18];
    const int*   species      = (const int*)d_in[19];

    const size_t NF = (size_t)N_NODES * FCH;
    float* ws     = (float*)d_ws;
    float* hs     = ws;
    float* hv0    = ws + 1 * NF;
    float* hv1    = ws + 2 * NF;
    float* hv2    = ws + 3 * NF;
    float* agg_s  = ws + 4 * NF;
    float* agg_v0 = ws + 5 * NF;
    float* agg_v1 = ws + 6 * NF;
    float* agg_v2 = ws + 7 * NF;
    int* counts   = (int*)(ws + 8 * NF);      // [N]
    int* cursor   = counts + N_NODES;         // [N] -> row_end after k_permute
    int* perm     = cursor + N_NODES;         // [E]

    float* out       = (float*)d_out;
    float* feats     = out + N_NODES;   // final feats output
    float* self_conn = feats;           // scratch until epilogue overwrites

    hipMemsetAsync(counts, 0, N_NODES * sizeof(int), stream);

    k_node_pre<<<N_NODES / NT1, 128, 0, stream>>>(
        node_scalars, node_vectors, w_skip, w_up0, w_up1, species,
        hs, hv0, hv1, hv2, self_conn);

    k_hist<<<N_EDGES / 256, 256, 0, stream>>>(receivers, counts);
    k_scan<<<1, 1024, 0, stream>>>(counts, cursor);
    k_permute<<<N_EDGES / 256, 256, 0, stream>>>(receivers, cursor, perm);

    k_edge<<<N_NODES / NB, 256, 0, stream>>>(
        vectors, radial, mlp_w1, mlp_w2, mlp_w3, mlp_w4,
        hs, hv0, hv1, hv2, senders, receivers, cursor, perm,
        agg_s, agg_v0, agg_v1, agg_v2);

    k_epilogue<<<N_NODES / NT1, 128, 0, stream>>>(
        agg_s, agg_v0, agg_v1, agg_v2, self_conn, species,
        w_down0, w_down1, w_sc, w_post, w_read1, w_read2,
        out, feats);
}

// Round 6
// 6808.636 us; speedup vs baseline: 1.2163x; 1.2163x over previous
//
#include <hip/hip_runtime.h>
#include <math.h>

// MACE layer, f32. Round 6: spill-free k_edge via loop inversion. R5 post-mortem:
// WRITE still 5.96GB = scratch spills of ev[48 regs] held across w4-restage
// barriers; 20 barriers/chunk made it latency-bound. Fix: stage each w4 path
// slice ONCE per chunk (5 stages, 15 barriers/chunk), re-gather es/ev fragments
// per path inside the barrier-free region (L2-hit re-reads), flush TP straight
// to LDS tile. Peak live ~96 VGPRs, nothing live across barriers -> no scratch.
// K1: node pre   Ksort: hist/scan/permute   K2: node-owned fused edge kernel
// K3: epilogue

#define N_NODES 32768
#define N_EDGES 524288
#define FCH 128
#define NBASIS 8
#define HDIM 64
#define CE 64      // edge chunk per block in K2
#define NB 4       // receiver nodes owned per block in K2
#define NT1 8      // nodes per block in K1/K3

__device__ __forceinline__ float silu(float x) { return x / (1.0f + __expf(-x)); }

constexpr float INV_SQRT128  = 0.08838834764831845f;
constexpr float INV_SQRT8    = 0.35355339059327373f;
constexpr float INV_64       = 0.125f;                 // 1/sqrt(64)
constexpr float INV_SQRT3    = 0.5773502691896258f;
constexpr float INV_SQRT2    = 0.7071067811865476f;
constexpr float INV_SQRT10   = 0.31622776601683794f;
constexpr float INV_SQRT1280 = 0.027950849718747374f;  // 1/sqrt(F*Z)
constexpr float INV_SQRT16   = 0.25f;
constexpr float EPSN         = 0.125f;

// ---------------------------------------------------------------- K1: node pre
__global__ __launch_bounds__(128) void k_node_pre(
    const float* __restrict__ ns, const float* __restrict__ nv,
    const float* __restrict__ w_skip, const float* __restrict__ w_up0,
    const float* __restrict__ w_up1, const int* __restrict__ species,
    float* __restrict__ hs, float* __restrict__ hv0, float* __restrict__ hv1,
    float* __restrict__ hv2, float* __restrict__ self_conn)
{
    __shared__ float ls[NT1][FCH];
    __shared__ float lv[3][NT1][FCH];
    __shared__ int lsp[NT1];
    const int g  = threadIdx.x;
    const int n0 = blockIdx.x * NT1;

    #pragma unroll
    for (int n = 0; n < NT1; ++n)
        ls[n][g] = ns[(size_t)(n0 + n) * FCH + g];
    for (int idx = g; idx < NT1 * FCH; idx += 128) {
        int n = idx >> 7, f = idx & 127;
        const float* src = nv + ((size_t)(n0 + n) * FCH + f) * 3;
        lv[0][n][f] = src[0];
        lv[1][n][f] = src[1];
        lv[2][n][f] = src[2];
    }
    if (g < NT1) lsp[g] = species[n0 + g];
    __syncthreads();

    const float* wk[NT1];
    #pragma unroll
    for (int n = 0; n < NT1; ++n)
        wk[n] = w_skip + (size_t)lsp[n] * FCH * FCH + g;

    float a_s[NT1], a0[NT1], a1[NT1], a2[NT1], a_k[NT1];
    #pragma unroll
    for (int n = 0; n < NT1; ++n) { a_s[n]=0; a0[n]=0; a1[n]=0; a2[n]=0; a_k[n]=0; }

    #pragma unroll 2
    for (int f = 0; f < FCH; ++f) {
        float u0 = w_up0[f * FCH + g];
        float u1 = w_up1[f * FCH + g];
        #pragma unroll
        for (int n = 0; n < NT1; ++n) {
            float s = ls[n][f];
            a_s[n] += s * u0;
            a0[n]  += lv[0][n][f] * u1;
            a1[n]  += lv[1][n][f] * u1;
            a2[n]  += lv[2][n][f] * u1;
            a_k[n] += s * wk[n][(size_t)f * FCH];
        }
    }
    #pragma unroll
    for (int n = 0; n < NT1; ++n) {
        size_t o = (size_t)(n0 + n) * FCH + g;
        hs[o]  = a_s[n] * INV_SQRT128;
        hv0[o] = a0[n]  * INV_SQRT128;
        hv1[o] = a1[n]  * INV_SQRT128;
        hv2[o] = a2[n]  * INV_SQRT128;
        self_conn[o] = a_k[n] * INV_SQRT1280;
    }
}

// ---------------------------------------------------------------- sort kernels
__global__ __launch_bounds__(256) void k_hist(
    const int* __restrict__ recv, int* __restrict__ counts)
{
    int e = blockIdx.x * 256 + threadIdx.x;
    atomicAdd(&counts[recv[e]], 1);
}

__global__ __launch_bounds__(1024) void k_scan(
    const int* __restrict__ counts, int* __restrict__ cursor)
{
    __shared__ int part[1024];
    const int t  = threadIdx.x;
    const int b0 = t * 32;
    int local[32];
    int s = 0;
    #pragma unroll
    for (int i = 0; i < 32; ++i) { local[i] = s; s += counts[b0 + i]; }
    part[t] = s;
    __syncthreads();
    for (int off = 1; off < 1024; off <<= 1) {
        int v   = part[t];
        int add = (t >= off) ? part[t - off] : 0;
        __syncthreads();
        part[t] = v + add;
        __syncthreads();
    }
    int base = (t == 0) ? 0 : part[t - 1];
    #pragma unroll
    for (int i = 0; i < 32; ++i) cursor[b0 + i] = base + local[i];
}

__global__ __launch_bounds__(256) void k_permute(
    const int* __restrict__ recv, int* __restrict__ cursor,
    int* __restrict__ perm)
{
    int e = blockIdx.x * 256 + threadIdx.x;
    int pos = atomicAdd(&cursor[recv[e]], 1);
    perm[pos] = e;
}

// ---------------------------------------------------------------- K2: edges
// Block owns nodes [blockIdx.x*NB, +NB); their in-edges contiguous in perm.
// Per chunk: radial MLP -> hA; then per path p: stage w4[p] once, both halves
// re-gather fragments and flush TP into LDS tile. No global atomics, no spills.
__global__ __launch_bounds__(256, 2) void k_edge(
    const float* __restrict__ vectors, const float* __restrict__ radial,
    const float* __restrict__ w1, const float* __restrict__ w2,
    const float* __restrict__ w3, const float* __restrict__ w4,
    const float* __restrict__ hs, const float* __restrict__ hv0,
    const float* __restrict__ hv1, const float* __restrict__ hv2,
    const int* __restrict__ senders, const int* __restrict__ receivers,
    const int* __restrict__ row_end, const int* __restrict__ perm,
    float* __restrict__ agg_s, float* __restrict__ agg_v0,
    float* __restrict__ agg_v1, float* __restrict__ agg_v2)
{
    __shared__ __align__(16) float lrad[CE * NBASIS];   // 2KB
    __shared__ __align__(16) float hA[CE * HDIM];       // 16KB
    __shared__ __align__(16) float hB[CE * HDIM];       // 16KB
    __shared__ __align__(16) float w4lds[HDIM * FCH];   // 32KB (one path slice)
    __shared__ float lY[CE][3];
    __shared__ int leid[CE], lsend[CE], lnl[CE];
    __shared__ __align__(16) float laccS[NB * FCH];     // 2KB each
    __shared__ __align__(16) float laccV0[NB * FCH];
    __shared__ __align__(16) float laccV1[NB * FCH];
    __shared__ __align__(16) float laccV2[NB * FCH];
    __shared__ int sse[2];

    const int tid   = threadIdx.x;
    const int nbase = blockIdx.x * NB;

    if (tid == 0) {
        sse[0] = (nbase == 0) ? 0 : row_end[nbase - 1];
        sse[1] = row_end[nbase + NB - 1];
    }
    for (int i = tid; i < NB * FCH; i += 256) {
        laccS[i] = 0.f; laccV0[i] = 0.f; laccV1[i] = 0.f; laccV2[i] = 0.f;
    }
    __syncthreads();
    const int start = sse[0], end = sse[1];

    const int k   = tid & 63;
    const int grp = tid >> 6;       // wave id, 16 edge slots each (phase A)
    const int fq  = (tid & 31) * 4; // channel quad base
    const int eg  = tid >> 5;       // 0..7, 8 edge slots each (phase B)
    const int rot = (tid >> 3) & 3; // bank rotation for LDS-tile atomics

    for (int c0 = start; c0 < end; c0 += CE) {
        const int nc = min(CE, end - c0);

        __syncthreads();   // prior chunk's readers of hA/lsend/lY done
        if (tid < CE) leid[tid] = (tid < nc) ? perm[c0 + tid] : -1;
        __syncthreads();
        if (tid < CE) {
            int eid = leid[tid];
            if (eid >= 0) {
                float vx = vectors[(size_t)eid * 3 + 0];
                float vy = vectors[(size_t)eid * 3 + 1];
                float vz = vectors[(size_t)eid * 3 + 2];
                float rn = 1.0f / (sqrtf(vx * vx + vy * vy + vz * vz) + 1e-9f);
                lY[tid][0] = vx * rn; lY[tid][1] = vy * rn; lY[tid][2] = vz * rn;
                lsend[tid] = senders[eid];
                lnl[tid]   = receivers[eid] - nbase;   // 0..NB-1
            } else {
                lY[tid][0] = 0.f; lY[tid][1] = 0.f; lY[tid][2] = 0.f;
                lsend[tid] = 0;
                lnl[tid]   = -1;
            }
        }
        for (int idx = tid; idx < CE * NBASIS; idx += 256) {
            int slot = idx >> 3;
            int eid  = leid[slot];
            lrad[idx] = (eid >= 0) ? radial[(size_t)eid * NBASIS + (idx & 7)] : 0.f;
        }
        __syncthreads();

        const int e_lo = grp * 16;
        const int e_hi = min(e_lo + 16, nc);

        // radial MLP: layer 1 (8->64)
        if (e_lo < nc) {
            float w1c[NBASIS];
            #pragma unroll
            for (int j = 0; j < NBASIS; ++j) w1c[j] = w1[j * HDIM + k];
            for (int e = e_lo; e < e_hi; ++e) {
                float acc = 0.f;
                #pragma unroll
                for (int j = 0; j < NBASIS; ++j) acc += lrad[e * NBASIS + j] * w1c[j];
                hA[e * HDIM + k] = silu(acc * INV_SQRT8);
            }
        }
        __syncthreads();
        // layer 2 (64->64)
        if (e_lo < nc) {
            float wc[HDIM];
            #pragma unroll
            for (int j = 0; j < HDIM; ++j) wc[j] = w2[j * HDIM + k];
            for (int e = e_lo; e < e_hi; ++e) {
                float acc = 0.f;
                #pragma unroll
                for (int j = 0; j < HDIM; ++j) acc += hA[e * HDIM + j] * wc[j];
                hB[e * HDIM + k] = silu(acc * INV_64);
            }
        }
        __syncthreads();
        // layer 3 (64->64)
        if (e_lo < nc) {
            float wc[HDIM];
            #pragma unroll
            for (int j = 0; j < HDIM; ++j) wc[j] = w3[j * HDIM + k];
            for (int e = e_lo; e < e_hi; ++e) {
                float acc = 0.f;
                #pragma unroll
                for (int j = 0; j < HDIM; ++j) acc += hB[e * HDIM + j] * wc[j];
                hA[e * HDIM + k] = silu(acc * INV_64);
            }
        }

        // Phase B: per path p, stage w4[p] once, then both halves.
        #pragma unroll
        for (int p = 0; p < 5; ++p) {
            __syncthreads();   // phase-A hA done (p=0) / prior path's readers done
            for (int idx = tid; idx < HDIM * 32; idx += 256) {
                int j = idx >> 5;
                int f = (idx & 31) * 4;
                *(float4*)&w4lds[j * FCH + f] =
                    *(const float4*)(w4 + (size_t)j * 640 + p * FCH + f);
            }
            __syncthreads();

            for (int half = 0; half < 2; ++half) {
                const int e_base = eg * 8 + half * 4;
                if (e_base >= nc) continue;
                int eL[4];
                #pragma unroll
                for (int q = 0; q < 4; ++q) eL[q] = e_base + q;

                // mix for this path: mx[q][c]
                float mx[4][4];
                #pragma unroll
                for (int q = 0; q < 4; ++q)
                    #pragma unroll
                    for (int c = 0; c < 4; ++c) mx[q][c] = 0;
                for (int j4 = 0; j4 < 16; ++j4) {
                    float4 wj0 = *(float4*)&w4lds[(j4 * 4 + 0) * FCH + fq];
                    float4 wj1 = *(float4*)&w4lds[(j4 * 4 + 1) * FCH + fq];
                    float4 wj2 = *(float4*)&w4lds[(j4 * 4 + 2) * FCH + fq];
                    float4 wj3 = *(float4*)&w4lds[(j4 * 4 + 3) * FCH + fq];
                    #pragma unroll
                    for (int q = 0; q < 4; ++q) {
                        float4 h4 = *(float4*)&hA[eL[q] * HDIM + j4 * 4];
                        mx[q][0] += h4.x*wj0.x + h4.y*wj1.x + h4.z*wj2.x + h4.w*wj3.x;
                        mx[q][1] += h4.x*wj0.y + h4.y*wj1.y + h4.z*wj2.y + h4.w*wj3.y;
                        mx[q][2] += h4.x*wj0.z + h4.y*wj1.z + h4.z*wj2.z + h4.w*wj3.z;
                        mx[q][3] += h4.x*wj0.w + h4.y*wj1.w + h4.z*wj2.w + h4.w*wj3.w;
                    }
                }

                if (p == 0 || p == 2) {
                    // needs es
                    float es[4][4];
                    #pragma unroll
                    for (int q = 0; q < 4; ++q) {
                        float4 t = *(const float4*)(hs + (size_t)lsend[eL[q]] * FCH + fq);
                        es[q][0]=t.x; es[q][1]=t.y; es[q][2]=t.z; es[q][3]=t.w;
                    }
                    #pragma unroll
                    for (int q = 0; q < 4; ++q) {
                        int nl = lnl[eL[q]];
                        if (nl < 0) continue;
                        int b = nl * FCH + fq;
                        if (p == 0) {
                            #pragma unroll
                            for (int c = 0; c < 4; ++c) {
                                int cc = (c + rot) & 3;
                                atomicAdd(&laccS[b + cc], mx[q][cc] * es[q][cc]);
                            }
                        } else {
                            float Yx = lY[eL[q]][0], Yy = lY[eL[q]][1], Yz = lY[eL[q]][2];
                            #pragma unroll
                            for (int c = 0; c < 4; ++c) {
                                int cc = (c + rot) & 3;
                                float t = mx[q][cc] * es[q][cc];
                                atomicAdd(&laccV0[b + cc], t * Yx);
                                atomicAdd(&laccV1[b + cc], t * Yy);
                                atomicAdd(&laccV2[b + cc], t * Yz);
                            }
                        }
                    }
                } else {
                    // needs ev
                    float ev0[4][4], ev1[4][4], ev2[4][4];
                    #pragma unroll
                    for (int q = 0; q < 4; ++q) {
                        size_t o = (size_t)lsend[eL[q]] * FCH + fq;
                        float4 t;
                        t = *(const float4*)(hv0 + o);
                        ev0[q][0]=t.x; ev0[q][1]=t.y; ev0[q][2]=t.z; ev0[q][3]=t.w;
                        t = *(const float4*)(hv1 + o);
                        ev1[q][0]=t.x; ev1[q][1]=t.y; ev1[q][2]=t.z; ev1[q][3]=t.w;
                        t = *(const float4*)(hv2 + o);
                        ev2[q][0]=t.x; ev2[q][1]=t.y; ev2[q][2]=t.z; ev2[q][3]=t.w;
                    }
                    #pragma unroll
                    for (int q = 0; q < 4; ++q) {
                        int nl = lnl[eL[q]];
                        if (nl < 0) continue;
                        int b = nl * FCH + fq;
                        float Yx = lY[eL[q]][0], Yy = lY[eL[q]][1], Yz = lY[eL[q]][2];
                        if (p == 1) {
                            #pragma unroll
                            for (int c = 0; c < 4; ++c) {
                                int cc = (c + rot) & 3;
                                float d = ev0[q][cc]*Yx + ev1[q][cc]*Yy + ev2[q][cc]*Yz;
                                atomicAdd(&laccS[b + cc], mx[q][cc] * d * INV_SQRT3);
                            }
                        } else if (p == 3) {
                            #pragma unroll
                            for (int c = 0; c < 4; ++c) {
                                int cc = (c + rot) & 3;
                                float m = mx[q][cc];
                                atomicAdd(&laccV0[b + cc], m * ev0[q][cc]);
                                atomicAdd(&laccV1[b + cc], m * ev1[q][cc]);
                                atomicAdd(&laccV2[b + cc], m * ev2[q][cc]);
                            }
                        } else {
                            #pragma unroll
                            for (int c = 0; c < 4; ++c) {
                                int cc = (c + rot) & 3;
                                float m = mx[q][cc] * INV_SQRT2;
                                float cx = ev1[q][cc]*Yz - ev2[q][cc]*Yy;
                                float cy = ev2[q][cc]*Yx - ev0[q][cc]*Yz;
                                float cz = ev0[q][cc]*Yy - ev1[q][cc]*Yx;
                                atomicAdd(&laccV0[b + cc], m * cx);
                                atomicAdd(&laccV1[b + cc], m * cy);
                                atomicAdd(&laccV2[b + cc], m * cz);
                            }
                        }
                    }
                }
            } // half
        } // p
    } // chunk

    __syncthreads();
    for (int i = tid; i < NB * FCH; i += 256) {
        int nl = i >> 7;
        int ch = i & 127;
        size_t o = (size_t)(nbase + nl) * FCH + ch;
        agg_s[o]  = laccS[i]  * INV_64;
        agg_v0[o] = laccV0[i] * INV_64;
        agg_v1[o] = laccV1[i] * INV_64;
        agg_v2[o] = laccV2[i] * INV_64;
    }
}

// ---------------------------------------------------------------- K3: epilogue
__global__ __launch_bounds__(128) void k_epilogue(
    const float* __restrict__ agg_s, const float* __restrict__ agg_v0,
    const float* __restrict__ agg_v1, const float* __restrict__ agg_v2,
    const float* __restrict__ self_conn, const int* __restrict__ species,
    const float* __restrict__ w_down0, const float* __restrict__ w_down1,
    const float* __restrict__ w_sc, const float* __restrict__ w_post,
    const float* __restrict__ w_read1, const float* __restrict__ w_read2,
    float* __restrict__ out0, float* __restrict__ feats_out)
{
    __shared__ float lS[NT1][FCH];
    __shared__ float lV[3][NT1][FCH];
    __shared__ float fA[NT1][FCH];
    __shared__ float fB[NT1][FCH];
    __shared__ int lsp[NT1];
    const int g  = threadIdx.x;
    const int n0 = blockIdx.x * NT1;

    #pragma unroll
    for (int n = 0; n < NT1; ++n) {
        size_t o = (size_t)(n0 + n) * FCH + g;
        lS[n][g]    = agg_s[o]  * EPSN;
        lV[0][n][g] = agg_v0[o] * EPSN;
        lV[1][n][g] = agg_v1[o] * EPSN;
        lV[2][n][g] = agg_v2[o] * EPSN;
    }
    if (g < NT1) lsp[g] = species[n0 + g];
    __syncthreads();

    float xs[NT1], xv0[NT1], xv1[NT1], xv2[NT1];
    #pragma unroll
    for (int n = 0; n < NT1; ++n) { xs[n]=0; xv0[n]=0; xv1[n]=0; xv2[n]=0; }
    #pragma unroll 2
    for (int f = 0; f < FCH; ++f) {
        float d0 = w_down0[f * FCH + g];
        float d1 = w_down1[f * FCH + g];
        #pragma unroll
        for (int n = 0; n < NT1; ++n) {
            xs[n]  += lS[n][f] * d0;
            xv0[n] += lV[0][n][f] * d1;
            xv1[n] += lV[1][n][f] * d1;
            xv2[n] += lV[2][n][f] * d1;
        }
    }
    #pragma unroll
    for (int n = 0; n < NT1; ++n) {
        float s  = xs[n]  * INV_SQRT128;
        float v0 = xv0[n] * INV_SQRT128;
        float v1 = xv1[n] * INV_SQRT128;
        float v2 = xv2[n] * INV_SQRT128;
        int z = lsp[n];
        float wz0 = w_sc[((size_t)z * 3 + 0) * FCH + g] * INV_SQRT10;
        float wz1 = w_sc[((size_t)z * 3 + 1) * FCH + g] * INV_SQRT10;
        float wz2 = w_sc[((size_t)z * 3 + 2) * FCH + g] * INV_SQRT10;
        fA[n][g] = wz0 * s + wz1 * s * s + wz2 * (v0*v0 + v1*v1 + v2*v2);
    }
    __syncthreads();

    float fc[NT1];
    #pragma unroll
    for (int n = 0; n < NT1; ++n) fc[n] = 0;
    #pragma unroll 2
    for (int f = 0; f < FCH; ++f) {
        float wp = w_post[f * FCH + g];
        #pragma unroll
        for (int n = 0; n < NT1; ++n) fc[n] += fA[n][f] * wp;
    }
    #pragma unroll
    for (int n = 0; n < NT1; ++n) {
        size_t o = (size_t)(n0 + n) * FCH + g;
        float v = fc[n] * INV_SQRT128 + self_conn[o];
        fB[n][g] = v;
        feats_out[o] = v;
    }
    __syncthreads();

    const int n2 = g >> 4, r = g & 15;
    float acc = 0.f;
    for (int f = 0; f < FCH; ++f) acc += fB[n2][f] * w_read1[f * 16 + r];
    float t = silu(acc * INV_SQRT128);
    float val = t * w_read2[r];
    val += __shfl_down(val, 8, 16);
    val += __shfl_down(val, 4, 16);
    val += __shfl_down(val, 2, 16);
    val += __shfl_down(val, 1, 16);
    if (r == 0) out0[n0 + n2] = val * INV_SQRT16;
}

// ---------------------------------------------------------------- launch
extern "C" void kernel_launch(void* const* d_in, const int* in_sizes, int n_in,
                              void* d_out, int out_size, void* d_ws, size_t ws_size,
                              hipStream_t stream) {
    (void)in_sizes; (void)n_in; (void)out_size; (void)ws_size;
    const float* vectors      = (const float*)d_in[0];
    const float* node_scalars = (const float*)d_in[1];
    const float* node_vectors = (const float*)d_in[2];
    const float* radial       = (const float*)d_in[3];
    const float* w_skip       = (const float*)d_in[4];
    const float* w_up0        = (const float*)d_in[5];
    const float* w_up1        = (const float*)d_in[6];
    const float* mlp_w1       = (const float*)d_in[7];
    const float* mlp_w2       = (const float*)d_in[8];
    const float* mlp_w3       = (const float*)d_in[9];
    const float* mlp_w4       = (const float*)d_in[10];
    const float* w_down0      = (const float*)d_in[11];
    const float* w_down1      = (const float*)d_in[12];
    const float* w_sc         = (const float*)d_in[13];
    const float* w_post       = (const float*)d_in[14];
    const float* w_read1      = (const float*)d_in[15];
    const float* w_read2      = (const float*)d_in[16];
    const int*   senders      = (const int*)d_in[17];
    const int*   receivers    = (const int*)d_in[18];
    const int*   species      = (const int*)d_in[19];

    const size_t NF = (size_t)N_NODES * FCH;
    float* ws     = (float*)d_ws;
    float* hs     = ws;
    float* hv0    = ws + 1 * NF;
    float* hv1    = ws + 2 * NF;
    float* hv2    = ws + 3 * NF;
    float* agg_s  = ws + 4 * NF;
    float* agg_v0 = ws + 5 * NF;
    float* agg_v1 = ws + 6 * NF;
    float* agg_v2 = ws + 7 * NF;
    int* counts   = (int*)(ws + 8 * NF);      // [N]
    int* cursor   = counts + N_NODES;         // [N] -> row_end after k_permute
    int* perm     = cursor + N_NODES;         // [E]

    float* out       = (float*)d_out;
    float* feats     = out + N_NODES;   // final feats output
    float* self_conn = feats;           // scratch until epilogue overwrites

    hipMemsetAsync(counts, 0, N_NODES * sizeof(int), stream);

    k_node_pre<<<N_NODES / NT1, 128, 0, stream>>>(
        node_scalars, node_vectors, w_skip, w_up0, w_up1, species,
        hs, hv0, hv1, hv2, self_conn);

    k_hist<<<N_EDGES / 256, 256, 0, stream>>>(receivers, counts);
    k_scan<<<1, 1024, 0, stream>>>(counts, cursor);
    k_permute<<<N_EDGES / 256, 256, 0, stream>>>(receivers, cursor, perm);

    k_edge<<<N_NODES / NB, 256, 0, stream>>>(
        vectors, radial, mlp_w1, mlp_w2, mlp_w3, mlp_w4,
        hs, hv0, hv1, hv2, senders, receivers, cursor, perm,
        agg_s, agg_v0, agg_v1, agg_v2);

    k_epilogue<<<N_NODES / NT1, 128, 0, stream>>>(
        agg_s, agg_v0, agg_v1, agg_v2, self_conn, species,
        w_down0, w_down1, w_sc, w_post, w_read1, w_read2,
        out, feats);
}